// Round 11
// baseline (339.828 us; speedup 1.0000x reference)
//
#include <hip/hip_runtime.h>

#define D 64
#define CAP 64          // per-node bucket capacity (avg degree 16; P(>64) ~ 1e-20)
#define WQ_BITS 15
#define WQ_MAX 32767.0f
#define NS 16           // shards of 8192 nodes; s%8 -> XCD round-robin
#define SHBITS 13
#define OVCAP 131072

typedef int      int4v   __attribute__((ext_vector_type(4)));
typedef float    float4v __attribute__((ext_vector_type(4)));
typedef unsigned uint2v  __attribute__((ext_vector_type(2)));

__device__ __forceinline__ ushort f2bf(float x) {
    unsigned u = __float_as_uint(x);
    unsigned r = (u + 0x7fff + ((u >> 16) & 1)) >> 16;  // round-to-nearest-even
    return (ushort)r;
}
__device__ __forceinline__ float bf2f(ushort u) {
    return __uint_as_float(((unsigned)u) << 16);
}

// ---------------------------------------------------------------------------
// P0: per-shard edge histogram. 1 LDS atomic per EDGE (round-9 lesson: the
// killer was 64 LDS atomics per lane-edge; this is 256x lighter).
__global__ __launch_bounds__(256) void shard_count_kernel(
    const int* __restrict__ dst, int* __restrict__ shardCnt, int E)
{
    __shared__ int hgram[NS];
    if (threadIdx.x < NS) hgram[threadIdx.x] = 0;
    __syncthreads();
    int stride = gridDim.x * 256;
    for (int e = blockIdx.x * 256 + threadIdx.x; e < E; e += stride) {
        int d = __builtin_nontemporal_load(&dst[e]);
        atomicAdd(&hgram[d >> SHBITS], 1);
    }
    __syncthreads();
    if (threadIdx.x < NS) atomicAdd(&shardCnt[threadIdx.x], hgram[threadIdx.x]);
}

// ---------------------------------------------------------------------------
// Exclusive scan of 16 shard counts -> shardBase[0..16], shardCur=base.
__global__ void shard_scan_kernel(const int* __restrict__ shardCnt,
                                  int* __restrict__ shardBase,
                                  int* __restrict__ shardCur)
{
    if (threadIdx.x == 0) {
        int acc = 0;
        for (int s = 0; s < NS; ++s) {
            shardBase[s] = acc; shardCur[s] = acc; acc += shardCnt[s];
        }
        shardBase[NS] = acc;
    }
}

// ---------------------------------------------------------------------------
// P1: partition edges into 16 exact-offset shard lists. Per 256-edge round:
// LDS rank alloc + 1 global atomic per (block,shard), then contiguous append
// (~16-entry 128 B runs). Sequential streams, each edge read ONCE (vs the
// round-8 scatter's 8x re-scan = 123 MB FETCH).
__global__ __launch_bounds__(256) void partition_kernel(
    const int* __restrict__ src, const int* __restrict__ dst,
    const float* __restrict__ w, int* __restrict__ shardCur,
    uint2* __restrict__ edgeBuf, int E)
{
    __shared__ int cnt[NS];
    __shared__ int gbase[NS];
    int tid = threadIdx.x;
    int stride = gridDim.x * 256;
    int rounds = (E + stride - 1) / stride;   // uniform across blocks
    int e = blockIdx.x * 256 + tid;

    for (int r = 0; r < rounds; ++r, e += stride) {
        if (tid < NS) cnt[tid] = 0;
        __syncthreads();
        int myShard = -1, pos = 0;
        uint2 entry = make_uint2(0u, 0u);
        if (e < E) {
            int d    = __builtin_nontemporal_load(&dst[e]);
            int s    = __builtin_nontemporal_load(&src[e]);
            float wr = __builtin_nontemporal_load(&w[e]);
            float wv = fminf(fmaxf(wr, 0.f), 1.f);
            unsigned wq = (unsigned)(wv * WQ_MAX + 0.5f);
            entry = make_uint2(((unsigned)s << WQ_BITS) | wq, (unsigned)d);
            myShard = d >> SHBITS;
            pos = atomicAdd(&cnt[myShard], 1);
        }
        __syncthreads();
        if (tid < NS) {
            int c = cnt[tid];
            gbase[tid] = (c > 0) ? atomicAdd(&shardCur[tid], c) : 0;
        }
        __syncthreads();
        if (myShard >= 0)
            edgeBuf[gbase[myShard] + pos] = entry;
        __syncthreads();   // gbase stable until all stores done
    }
}

// ---------------------------------------------------------------------------
// P2: scatter within shard. Block b -> shard b%16 (XCD b%8 owns shards s,s+8:
// 2x2 MB pairs windows, L2-resident; only ~1.6 MB of list streaming per XCD,
// so the window survives (rounds 5-8: 19.2 MB streams thrashed it).
__global__ __launch_bounds__(256) void scatter2_kernel(
    const uint2* __restrict__ edgeBuf, const int* __restrict__ shardBase,
    int* __restrict__ cursor, unsigned* __restrict__ pairs,
    uint2* __restrict__ ovList, int* __restrict__ ovCur)
{
    int s       = blockIdx.x & (NS - 1);
    int slice   = blockIdx.x >> 4;
    int nSlices = gridDim.x >> 4;
    int beg = shardBase[s], end = shardBase[s + 1];
    int len = end - beg;
    int per = (len + nSlices - 1) / nSlices;
    int lo = beg + slice * per;
    int hi = min(end, lo + per);
    for (int i = lo + threadIdx.x; i < hi; i += 256) {
        uint2v ev = __builtin_nontemporal_load((const uint2v*)&edgeBuf[i]);
        int d = (int)ev[1];
        int pos = atomicAdd(&cursor[d], 1);
        if (pos < CAP) {
            pairs[(size_t)d * CAP + pos] = ev[0];
        } else {
            int op = atomicAdd(ovCur, 1);
            if (op < OVCAP) ovList[op] = make_uint2(ev[0], ev[1]);
        }
    }
}

// ---------------------------------------------------------------------------
// Fused GEMM: out[n][j] = b[j] + sum_k h[n][k]*W[j][k]        (fp32)
//             g[n][j]   =        sum_k h[n][k]*W[j][64+k]     (bf16 store)
// 64 nodes/block, 4 nodes x 4 cols per thread, LDS-only inner reads,
// unroll 4 (round-2 lesson: full unroll -> 256 VGPR spill).
__global__ __launch_bounds__(256) void gemm_fused_kernel(
    const float* __restrict__ h, const float* __restrict__ W,
    const float* __restrict__ b, float* __restrict__ out,
    ushort* __restrict__ g, int N)
{
    __shared__ float Wt[128 * 64];  // Wt[k*64+j] = W[j*128+k]
    __shared__ float Xt[64 * 64];   // Xt[k*64+n] = h[(n0+n)*64+k]
    int tid = threadIdx.x;

    for (int idx = tid; idx < 128 * 64; idx += 256) {
        int j = idx & 63;
        int k = idx >> 6;
        Wt[k * 64 + j] = W[j * 128 + k];
    }

    int n0blk = blockIdx.x * 64;
    {
        int n = tid & 63;
        int krow = tid >> 6;  // 0..3
        int nn = min(n0blk + n, N - 1);
        #pragma unroll
        for (int c = 0; c < 4; ++c) {
            int k0 = (krow + c * 4) * 4;
            float4 v = *(const float4*)&h[(size_t)nn * D + k0];
            Xt[(k0 + 0) * 64 + n] = v.x;
            Xt[(k0 + 1) * 64 + n] = v.y;
            Xt[(k0 + 2) * 64 + n] = v.z;
            Xt[(k0 + 3) * 64 + n] = v.w;
        }
    }
    __syncthreads();

    int j0 = (tid & 15) * 4;
    int nb = (tid >> 4) * 4;

    float4 bv = *(const float4*)&b[j0];
    float accS[4][4], accG[4][4];
    #pragma unroll
    for (int i = 0; i < 4; ++i) {
        accS[i][0] = bv.x; accS[i][1] = bv.y; accS[i][2] = bv.z; accS[i][3] = bv.w;
        accG[i][0] = 0.f;  accG[i][1] = 0.f;  accG[i][2] = 0.f;  accG[i][3] = 0.f;
    }

    #pragma unroll 4
    for (int k = 0; k < 64; ++k) {
        float4 xv = *(const float4*)&Xt[k * 64 + nb];
        float4 w1 = *(const float4*)&Wt[k * 64 + j0];
        float4 w2 = *(const float4*)&Wt[(k + 64) * 64 + j0];
        #pragma unroll
        for (int i = 0; i < 4; ++i) {
            float x = (&xv.x)[i];
            accS[i][0] += x * w1.x; accS[i][1] += x * w1.y;
            accS[i][2] += x * w1.z; accS[i][3] += x * w1.w;
            accG[i][0] += x * w2.x; accG[i][1] += x * w2.y;
            accG[i][2] += x * w2.z; accG[i][3] += x * w2.w;
        }
    }

    #pragma unroll
    for (int i = 0; i < 4; ++i) {
        int n = n0blk + nb + i;
        if (n < N) {
            *(float4*)&out[(size_t)n * D + j0] =
                make_float4(accS[i][0], accS[i][1], accS[i][2], accS[i][3]);
            ushort4 gv;
            gv.x = f2bf(accG[i][0]); gv.y = f2bf(accG[i][1]);
            gv.z = f2bf(accG[i][2]); gv.w = f2bf(accG[i][3]);
            *(ushort4*)&g[(size_t)n * D + j0] = gv;
        }
    }
}

// ---------------------------------------------------------------------------
// Final: out[n] += sum over bucket(n) of w_e * g_bf16[src_e].
// One wave per node; <=64 codes in one coalesced 256 B load, shfl broadcast.
__global__ __launch_bounds__(256) void final_agg_kernel(
    const ushort* __restrict__ g, const unsigned* __restrict__ pairs,
    const int* __restrict__ cursor, float* __restrict__ out, int N)
{
    int wave = threadIdx.x >> 6;
    int lane = threadIdx.x & 63;
    int n = blockIdx.x * 4 + wave;
    if (n >= N) return;
    int cnt = min(cursor[n], CAP);
    unsigned mycode = pairs[(size_t)n * CAP + lane];  // coalesced 256 B
    float acc = out[(size_t)n * D + lane];

    const float wscale = 1.0f / WQ_MAX;
    int j = 0;
    for (; j + 16 <= cnt; j += 16) {
        unsigned c[16];
        float v[16];
        #pragma unroll
        for (int u = 0; u < 16; ++u) c[u] = __shfl(mycode, j + u);
        #pragma unroll
        for (int u = 0; u < 16; ++u)
            v[u] = bf2f(g[(size_t)(c[u] >> WQ_BITS) * D + lane]);
        #pragma unroll
        for (int u = 0; u < 16; ++u)
            acc += (float)(c[u] & 0x7fffu) * wscale * v[u];
    }
    for (; j + 4 <= cnt; j += 4) {
        unsigned c[4];
        float v[4];
        #pragma unroll
        for (int u = 0; u < 4; ++u) c[u] = __shfl(mycode, j + u);
        #pragma unroll
        for (int u = 0; u < 4; ++u)
            v[u] = bf2f(g[(size_t)(c[u] >> WQ_BITS) * D + lane]);
        #pragma unroll
        for (int u = 0; u < 4; ++u)
            acc += (float)(c[u] & 0x7fffu) * wscale * v[u];
    }
    for (; j < cnt; ++j) {
        unsigned c = __shfl(mycode, j);
        acc += (float)(c & 0x7fffu) * wscale *
               bf2f(g[(size_t)(c >> WQ_BITS) * D + lane]);
    }
    out[(size_t)n * D + lane] = acc;
}

// ---------------------------------------------------------------------------
// Overflow cleanup: one wave per overflow entry (empty in practice).
__global__ __launch_bounds__(256) void ov_kernel(
    const uint2* __restrict__ ovList, const int* __restrict__ ovCur,
    const ushort* __restrict__ g, float* __restrict__ out)
{
    int cnt = min(*ovCur, OVCAP);
    int lane = threadIdx.x & 63;
    int wv = blockIdx.x * 4 + (threadIdx.x >> 6);
    for (int i = wv; i < cnt; i += gridDim.x * 4) {
        uint2 en = ovList[i];
        int dn = (int)en.y;
        int sn = (int)(en.x >> WQ_BITS);
        float wt = (float)(en.x & 0x7fffu) * (1.0f / WQ_MAX);
        atomicAdd(&out[(size_t)dn * D + lane], wt * bf2f(g[(size_t)sn * D + lane]));
    }
}

// ---------------------------------------------------------------------------
// Fallback path (small ws / big N): round-1 kernels, known-good.
__global__ __launch_bounds__(256) void edge_scatter_kernel(
    const float* __restrict__ h, const float* __restrict__ w,
    const int* __restrict__ src, const int* __restrict__ dst,
    float* __restrict__ agg, int E)
{
    int e = blockIdx.x * 4 + (threadIdx.x >> 6);
    int lane = threadIdx.x & 63;
    if (e >= E) return;
    float val = w[e] * h[(size_t)src[e] * D + lane];
    atomicAdd(&agg[(size_t)dst[e] * D + lane], val);
}

__global__ __launch_bounds__(256) void out_linear_kernel(
    const float* __restrict__ h, const float* __restrict__ agg,
    const float* __restrict__ W, const float* __restrict__ b,
    float* __restrict__ out, int N)
{
    __shared__ float Wt[128 * 64];
    int lane = threadIdx.x & 63;
    int waveInBlock = threadIdx.x >> 6;
    int wavesPerBlock = blockDim.x >> 6;
    for (int idx = threadIdx.x; idx < 128 * 64; idx += blockDim.x) {
        int j = idx & 63;
        int k = idx >> 6;
        Wt[k * 64 + j] = W[j * 128 + k];
    }
    __syncthreads();
    float bj = b[lane];
    int wavesPerGrid = gridDim.x * wavesPerBlock;
    for (int n = blockIdx.x * wavesPerBlock + waveInBlock; n < N; n += wavesPerGrid) {
        float hreg = h[(size_t)n * D + lane];
        float areg = agg[(size_t)n * D + lane];
        float acc = bj;
        #pragma unroll
        for (int k = 0; k < 64; ++k) {
            float hk = __shfl(hreg, k, 64);
            float ak = __shfl(areg, k, 64);
            acc += hk * Wt[k * 64 + lane];
            acc += ak * Wt[(k + 64) * 64 + lane];
        }
        out[(size_t)n * D + lane] = acc;
    }
}

// ---------------------------------------------------------------------------
extern "C" void kernel_launch(void* const* d_in, const int* in_sizes, int n_in,
                              void* d_out, int out_size, void* d_ws, size_t ws_size,
                              hipStream_t stream) {
    const float* h   = (const float*)d_in[0];
    const float* w   = (const float*)d_in[1];
    const int*   src = (const int*)d_in[2];
    const int*   dst = (const int*)d_in[3];
    const float* W   = (const float*)d_in[4];
    const float* b   = (const float*)d_in[5];
    float* out = (float*)d_out;

    int N = in_sizes[0] / D;
    int E = in_sizes[1];

    auto align256 = [](size_t x) { return (x + 255) & ~(size_t)255; };
    // header: cursor[N] | shardCnt[16] | shardBase[17] | shardCur[16] | ovCur[1]
    size_t headerB = align256((size_t)N * 4 + (16 + 17 + 16 + 1) * 4 + 64);
    size_t pairsB  = align256((size_t)N * CAP * 4);                  // 25.6 MB
    size_t ovB     = align256((size_t)OVCAP * 8);                    // 1 MB
    size_t sharedB = align256(((size_t)E * 8 > (size_t)N * D * 2)
                                  ? (size_t)E * 8 : (size_t)N * D * 2);
    size_t need = headerB + pairsB + ovB + sharedB;

    if (ws_size >= need && N <= (1 << 17)) {
        char* p = (char*)d_ws;
        int* cursor    = (int*)p;
        int* shardCnt  = cursor + N;
        int* shardBase = shardCnt + 16;
        int* shardCur  = shardBase + 17;
        int* ovCur     = shardCur + 16;
        p += headerB;
        unsigned* pairs  = (unsigned*)p;  p += pairsB;
        uint2*    ovList = (uint2*)p;     p += ovB;
        uint2*    edgeBuf = (uint2*)p;            // dead after P2...
        ushort*   g       = (ushort*)p;           // ...then reused as g

        hipMemsetAsync(cursor, 0, headerB, stream);  // zeros cursor+counters

        shard_count_kernel<<<2048, 256, 0, stream>>>(dst, shardCnt, E);
        shard_scan_kernel<<<1, 64, 0, stream>>>(shardCnt, shardBase, shardCur);
        partition_kernel<<<2048, 256, 0, stream>>>(src, dst, w, shardCur,
                                                   edgeBuf, E);
        scatter2_kernel<<<2048, 256, 0, stream>>>(edgeBuf, shardBase, cursor,
                                                  pairs, ovList, ovCur);
        gemm_fused_kernel<<<(N + 63) / 64, 256, 0, stream>>>(h, W, b, out, g, N);
        final_agg_kernel<<<(N + 3) / 4, 256, 0, stream>>>(g, pairs, cursor, out, N);
        ov_kernel<<<64, 256, 0, stream>>>(ovList, ovCur, g, out);
    } else {
        float* agg = out;
        hipMemsetAsync(agg, 0, (size_t)N * D * 4, stream);
        edge_scatter_kernel<<<(E + 3) / 4, 256, 0, stream>>>(h, w, src, dst, agg, E);
        out_linear_kernel<<<2048, 256, 0, stream>>>(h, agg, W, b, out, N);
    }
}